// Round 3
// baseline (1097.034 us; speedup 1.0000x reference)
//
#include <hip/hip_runtime.h>
#include <hip/hip_bf16.h>

namespace {
constexpr int kB = 8;
constexpr int kC = 64;     // channels = embed dim
constexpr int kH = 48;
constexpr int kW = 48;
constexpr int kS = kH * kW;          // 2304 tokens
constexpr float kEps = 1.1920929e-07f;
}

// ---------------------------------------------------------------------------
// Kernel 1: transpose k and v from [B,C,S] fp32 -> [B,S,C] fp32
// 64x64 LDS tile; reads coalesced over s, writes coalesced over c.
// ---------------------------------------------------------------------------
__global__ __launch_bounds__(256) void kv_transpose(
    const float* __restrict__ kin, const float* __restrict__ vin,
    float* __restrict__ ksq, float* __restrict__ vsq) {
  __shared__ float tile[64][65];   // +1 pad
  const int zz = blockIdx.y;       // b*2 + which
  const int b = zz >> 1;
  const float* src = (zz & 1) ? vin : kin;
  float* dst = (zz & 1) ? vsq : ksq;
  const int s0 = blockIdx.x * 64;
  const int tx = threadIdx.x & 63;
  const int ty = threadIdx.x >> 6;  // 0..3
#pragma unroll
  for (int r = 0; r < 16; ++r) {
    int c = r * 4 + ty;
    tile[c][tx] = src[((size_t)b * kC + c) * kS + s0 + tx];
  }
  __syncthreads();
#pragma unroll
  for (int r = 0; r < 16; ++r) {
    int s = r * 4 + ty;
    dst[((size_t)b * kS + s0 + s) * kC + tx] = tile[tx][s];
  }
}

// ---------------------------------------------------------------------------
// Kernel 2: k path — RMSNorm over C then 64x64 projection (wk^T) + bk.
// One 64-thread wave per (b,s) row. kp[b,s,e] fp32.
// ---------------------------------------------------------------------------
__global__ __launch_bounds__(64) void k_proj(
    const float* __restrict__ ksq, const float* __restrict__ nk_w,
    const float* __restrict__ wk, const float* __restrict__ bk,
    float* __restrict__ kp) {
  __shared__ float kn[kC];
  const int s = blockIdx.x;
  const int b = blockIdx.y;
  const int t = threadIdx.x;          // channel
  const size_t row = (size_t)b * kS + s;

  float x = ksq[row * kC + t];
  float ssum = x * x;
#pragma unroll
  for (int off = 32; off; off >>= 1) ssum += __shfl_xor(ssum, off, 64);
  float rinv = rsqrtf(ssum * (1.0f / kC) + kEps);
  kn[t] = x * rinv * nk_w[t];
  __syncthreads();

  const float* wrow = wk + t * kC;    // row e=t of wk (contiguous, 256B aligned)
  float acc = bk[t];
#pragma unroll
  for (int c = 0; c < kC; c += 4) {
    float4 wv = *reinterpret_cast<const float4*>(wrow + c);
    acc = fmaf(kn[c + 0], wv.x, acc);
    acc = fmaf(kn[c + 1], wv.y, acc);
    acc = fmaf(kn[c + 2], wv.z, acc);
    acc = fmaf(kn[c + 3], wv.w, acc);
  }
  kp[row * kC + t] = acc;
}

// ---------------------------------------------------------------------------
// Kernel 3: q path — 3x3 SAME conv (cross-correlation, OIHW weights) fused
// with RMSNorm and projection (wq^T) + bq, then * 1/sqrt(head_dim)=0.25.
// One 64-thread wave per (b,s) pixel. LDS holds the 576 input taps in the
// same (ci*9+tap) order as the weight rows -> flat vectorized dot.
// ---------------------------------------------------------------------------
__global__ __launch_bounds__(64) void q_conv_proj(
    const float* __restrict__ q, const float* __restrict__ conv_w,
    const float* __restrict__ nq_w, const float* __restrict__ wq,
    const float* __restrict__ bq, float* __restrict__ qp) {
  __shared__ float qf[kC * 9];
  __shared__ float qn[kC];
  const int s = blockIdx.x;
  const int b = blockIdx.y;
  const int h = s / kW, w = s % kW;
  const int t = threadIdx.x;

  // stage taps for input channel ci = t
  const float* qb = q + ((size_t)b * kC + t) * (kH * kW);
#pragma unroll
  for (int tap = 0; tap < 9; ++tap) {
    int hh = h + tap / 3 - 1;
    int ww = w + tap % 3 - 1;
    float val = 0.f;
    if (hh >= 0 && hh < kH && ww >= 0 && ww < kW) val = qb[hh * kW + ww];
    qf[t * 9 + tap] = val;
  }
  __syncthreads();

  // conv output channel c = t : dot over 576 taps
  const float* wr = conv_w + t * (kC * 9);   // contiguous
  float acc = 0.f;
#pragma unroll 4
  for (int idx = 0; idx < kC * 9; idx += 4) {
    float4 wv = *reinterpret_cast<const float4*>(wr + idx);
    const float* qv = &qf[idx];               // broadcast across wave
    acc = fmaf(qv[0], wv.x, acc);
    acc = fmaf(qv[1], wv.y, acc);
    acc = fmaf(qv[2], wv.z, acc);
    acc = fmaf(qv[3], wv.w, acc);
  }

  // RMSNorm over the 64 conv outputs
  float ssum = acc * acc;
#pragma unroll
  for (int off = 32; off; off >>= 1) ssum += __shfl_xor(ssum, off, 64);
  float rinv = rsqrtf(ssum * (1.0f / kC) + kEps);
  qn[t] = acc * rinv * nq_w[t];
  __syncthreads();

  const float* prow = wq + t * kC;
  float a2 = bq[t];
#pragma unroll
  for (int c = 0; c < kC; c += 4) {
    float4 wv = *reinterpret_cast<const float4*>(prow + c);
    a2 = fmaf(qn[c + 0], wv.x, a2);
    a2 = fmaf(qn[c + 1], wv.y, a2);
    a2 = fmaf(qn[c + 2], wv.z, a2);
    a2 = fmaf(qn[c + 3], wv.w, a2);
  }
  qp[((size_t)b * kS + s) * kC + t] = a2 * 0.25f;
}

// ---------------------------------------------------------------------------
// Kernel 4: attention. One block per (b, 64-query tile), 256 threads.
// Sweep 1: online softmax stats (m,l) per (i,head); each thread owns (i=lane,
//          j-stripe=grp), 4 stripes merged via log-sum-exp in LDS.
// Sweep 2: head-combined weights w(i,j) = 0.25*sum_h e^{s-M_h}/L_h (single
//          writer per (i,j)), then PV accumulation O[i][d] from LDS tiles.
// Output: fp32 [B,S,C].
// ---------------------------------------------------------------------------
__global__ __launch_bounds__(256) void attn_kernel(
    const float* __restrict__ qp, const float* __restrict__ kp,
    const float* __restrict__ vsq, float* __restrict__ out) {
  __shared__ float ktile[64][68];   // row = j, 272B rows (16B aligned)
  __shared__ float vtile[64][68];
  __shared__ float wtT[64][68];     // [j][i] combined weights
  __shared__ float pm[4][64][4];    // per-stripe partial max  [grp][i][h]
  __shared__ float pl[4][64][4];    // per-stripe partial sum
  __shared__ float Mh[64][4];
  __shared__ float Lh[64][4];       // 1/L

  const int b = blockIdx.y;
  const int i0 = blockIdx.x * 64;
  const int t = threadIdx.x;
  const int lane = t & 63;
  const int grp = t >> 6;           // 0..3
  const int r = t >> 2;             // staging: row 0..63
  const int p = t & 3;              // staging: 16-float chunk

  // q row (i = i0+lane) into registers, all 64 dims
  float qreg[64];
  {
    const float4* qsrc = reinterpret_cast<const float4*>(
        qp + ((size_t)b * kS + i0 + lane) * kC);
#pragma unroll
    for (int d4 = 0; d4 < 16; ++d4) {
      float4 x = qsrc[d4];
      qreg[d4 * 4 + 0] = x.x; qreg[d4 * 4 + 1] = x.y;
      qreg[d4 * 4 + 2] = x.z; qreg[d4 * 4 + 3] = x.w;
    }
  }

  // ---- sweep 1: online (m,l) per head over this thread's j-stripe ----
  float m0 = -1e30f, m1 = -1e30f, m2 = -1e30f, m3 = -1e30f;
  float l0 = 0.f, l1 = 0.f, l2 = 0.f, l3 = 0.f;

  for (int jt = 0; jt < kS; jt += 64) {
    const float4* src = reinterpret_cast<const float4*>(
        kp + ((size_t)b * kS + jt + r) * kC + p * 16);
    float4* dstk = reinterpret_cast<float4*>(&ktile[r][p * 16]);
    dstk[0] = src[0]; dstk[1] = src[1]; dstk[2] = src[2]; dstk[3] = src[3];
    __syncthreads();
    for (int jj = 0; jj < 16; ++jj) {
      int j = grp * 16 + jj;
      const float* kr = &ktile[j][0];        // broadcast across wave
      float s0 = 0, s1 = 0, s2 = 0, s3 = 0;
#pragma unroll
      for (int d = 0; d < 16; ++d) {
        s0 = fmaf(qreg[d],      kr[d],      s0);
        s1 = fmaf(qreg[16 + d], kr[16 + d], s1);
        s2 = fmaf(qreg[32 + d], kr[32 + d], s2);
        s3 = fmaf(qreg[48 + d], kr[48 + d], s3);
      }
      float mn;
      mn = fmaxf(m0, s0); l0 = l0 * __expf(m0 - mn) + __expf(s0 - mn); m0 = mn;
      mn = fmaxf(m1, s1); l1 = l1 * __expf(m1 - mn) + __expf(s1 - mn); m1 = mn;
      mn = fmaxf(m2, s2); l2 = l2 * __expf(m2 - mn) + __expf(s2 - mn); m2 = mn;
      mn = fmaxf(m3, s3); l3 = l3 * __expf(m3 - mn) + __expf(s3 - mn); m3 = mn;
    }
    __syncthreads();
  }

  pm[grp][lane][0] = m0; pm[grp][lane][1] = m1;
  pm[grp][lane][2] = m2; pm[grp][lane][3] = m3;
  pl[grp][lane][0] = l0; pl[grp][lane][1] = l1;
  pl[grp][lane][2] = l2; pl[grp][lane][3] = l3;
  __syncthreads();
  {
    int ii = t & 63, h = t >> 6;   // 64 i x 4 h = 256 pairs
    float M = pm[0][ii][h];
    M = fmaxf(M, pm[1][ii][h]);
    M = fmaxf(M, pm[2][ii][h]);
    M = fmaxf(M, pm[3][ii][h]);
    float L = pl[0][ii][h] * __expf(pm[0][ii][h] - M)
            + pl[1][ii][h] * __expf(pm[1][ii][h] - M)
            + pl[2][ii][h] * __expf(pm[2][ii][h] - M)
            + pl[3][ii][h] * __expf(pm[3][ii][h] - M);
    Mh[ii][h] = M;
    Lh[ii][h] = 1.0f / L;
  }
  __syncthreads();
  const float Mr0 = Mh[lane][0], Mr1 = Mh[lane][1];
  const float Mr2 = Mh[lane][2], Mr3 = Mh[lane][3];
  const float Lr0 = Lh[lane][0], Lr1 = Lh[lane][1];
  const float Lr2 = Lh[lane][2], Lr3 = Lh[lane][3];

  // ---- sweep 2: combined weights + PV ----
  float O[16];
#pragma unroll
  for (int i = 0; i < 16; ++i) O[i] = 0.f;

  for (int jt = 0; jt < kS; jt += 64) {
    const float4* srck = reinterpret_cast<const float4*>(
        kp + ((size_t)b * kS + jt + r) * kC + p * 16);
    const float4* srcv = reinterpret_cast<const float4*>(
        vsq + ((size_t)b * kS + jt + r) * kC + p * 16);
    float4* dstk = reinterpret_cast<float4*>(&ktile[r][p * 16]);
    float4* dstv = reinterpret_cast<float4*>(&vtile[r][p * 16]);
    dstk[0] = srck[0]; dstk[1] = srck[1]; dstk[2] = srck[2]; dstk[3] = srck[3];
    dstv[0] = srcv[0]; dstv[1] = srcv[1]; dstv[2] = srcv[2]; dstv[3] = srcv[3];
    __syncthreads();

    // weights: thread (i=lane, j in grp stripe) -> single writer wtT[j][i]
    for (int jj = 0; jj < 16; ++jj) {
      int j = grp * 16 + jj;
      const float* kr = &ktile[j][0];
      float s0 = 0, s1 = 0, s2 = 0, s3 = 0;
#pragma unroll
      for (int d = 0; d < 16; ++d) {
        s0 = fmaf(qreg[d],      kr[d],      s0);
        s1 = fmaf(qreg[16 + d], kr[16 + d], s1);
        s2 = fmaf(qreg[32 + d], kr[32 + d], s2);
        s3 = fmaf(qreg[48 + d], kr[48 + d], s3);
      }
      float wgt = __expf(s0 - Mr0) * Lr0 + __expf(s1 - Mr1) * Lr1
                + __expf(s2 - Mr2) * Lr2 + __expf(s3 - Mr3) * Lr3;
      wtT[j][lane] = wgt * 0.25f;
    }
    __syncthreads();

    // PV: thread (d=lane, i-group=grp); w reads are wave-broadcast b128
    for (int j = 0; j < 64; ++j) {
      float vv = vtile[j][lane];
      const float4* wr4 = reinterpret_cast<const float4*>(&wtT[j][grp * 16]);
      float4 w0 = wr4[0], w1 = wr4[1], w2 = wr4[2], w3 = wr4[3];
      O[0]  = fmaf(w0.x, vv, O[0]);  O[1]  = fmaf(w0.y, vv, O[1]);
      O[2]  = fmaf(w0.z, vv, O[2]);  O[3]  = fmaf(w0.w, vv, O[3]);
      O[4]  = fmaf(w1.x, vv, O[4]);  O[5]  = fmaf(w1.y, vv, O[5]);
      O[6]  = fmaf(w1.z, vv, O[6]);  O[7]  = fmaf(w1.w, vv, O[7]);
      O[8]  = fmaf(w2.x, vv, O[8]);  O[9]  = fmaf(w2.y, vv, O[9]);
      O[10] = fmaf(w2.z, vv, O[10]); O[11] = fmaf(w2.w, vv, O[11]);
      O[12] = fmaf(w3.x, vv, O[12]); O[13] = fmaf(w3.y, vv, O[13]);
      O[14] = fmaf(w3.z, vv, O[14]); O[15] = fmaf(w3.w, vv, O[15]);
    }
    __syncthreads();
  }

#pragma unroll
  for (int i = 0; i < 16; ++i) {
    out[((size_t)b * kS + i0 + grp * 16 + i) * kC + lane] = O[i];
  }
}

// ---------------------------------------------------------------------------
extern "C" void kernel_launch(void* const* d_in, const int* in_sizes, int n_in,
                              void* d_out, int out_size, void* d_ws, size_t ws_size,
                              hipStream_t stream) {
  const float* q      = (const float*)d_in[0];
  const float* k      = (const float*)d_in[1];
  const float* v      = (const float*)d_in[2];
  const float* conv_w = (const float*)d_in[3];
  const float* nq_w   = (const float*)d_in[4];
  const float* nk_w   = (const float*)d_in[5];
  const float* wq     = (const float*)d_in[6];
  const float* bq     = (const float*)d_in[7];
  const float* wk     = (const float*)d_in[8];
  const float* bk     = (const float*)d_in[9];
  float* out = (float*)d_out;   // reference returns float32 -> d_out is fp32

  const size_t N = (size_t)kB * kS * kC;   // 1,179,648
  float* ws  = (float*)d_ws;
  float* ksq = ws;            // [B,S,C] fp32
  float* vsq = ws + N;        // [B,S,C] fp32
  float* kp  = ws + 2 * N;    // [B,S,E] fp32
  float* qp  = ws + 3 * N;    // [B,S,E] fp32  (total 18.9 MB of d_ws)

  kv_transpose<<<dim3(kS / 64, kB * 2), 256, 0, stream>>>(k, v, ksq, vsq);
  k_proj<<<dim3(kS, kB), 64, 0, stream>>>(ksq, nk_w, wk, bk, kp);
  q_conv_proj<<<dim3(kS, kB), 64, 0, stream>>>(q, conv_w, nq_w, wq, bq, qp);
  attn_kernel<<<dim3(kS / 64, kB), 256, 0, stream>>>(qp, kp, vsq, out);
}

// Round 4
// 596.140 us; speedup vs baseline: 1.8402x; 1.8402x over previous
//
#include <hip/hip_runtime.h>
#include <hip/hip_bf16.h>

namespace {
constexpr int kB = 8;
constexpr int kC = 64;
constexpr int kH = 48;
constexpr int kW = 48;
constexpr int kS = kH * kW;          // 2304
constexpr float kEps = 1.1920929e-07f;
}

typedef __attribute__((ext_vector_type(8))) short short8;   // 8 bf16 (4 VGPR)
typedef __attribute__((ext_vector_type(4))) float f32x4;

// fp32 -> bf16 (round-nearest-even), bit-level
__device__ __forceinline__ short f2bf(float x) {
  unsigned u = __float_as_uint(x);
  u += 0x7fffu + ((u >> 16) & 1u);
  return (short)(u >> 16);
}

// ---------------------------------------------------------------------------
// k path: transpose-load + RMSNorm + 64x64 projection -> kp bf16 [B,S,64]
// grid (36, 8), 256 threads.
// ---------------------------------------------------------------------------
__global__ __launch_bounds__(256) void k_path(
    const float* __restrict__ k, const float* __restrict__ nk_w,
    const float* __restrict__ wk, const float* __restrict__ bk,
    short* __restrict__ kp) {
  __shared__ float kt[64][65];     // [s][c]
  __shared__ float knT[64][68];    // [c][s] normalized
  __shared__ float psum[4][64];
  __shared__ float rstd[64];
  const int b = blockIdx.y;
  const int s0 = blockIdx.x * 64;
  const int t = threadIdx.x;
  const int sl = t & 63;           // s lane
  const int cg = t >> 6;           // c group 0..3

  float ps = 0.f;
#pragma unroll
  for (int cc = 0; cc < 16; ++cc) {
    int c = cg * 16 + cc;
    float x = k[((size_t)b * kC + c) * kS + s0 + sl];   // coalesced over s
    kt[sl][c] = x;
    ps = fmaf(x, x, ps);
  }
  psum[cg][sl] = ps;
  __syncthreads();
  if (t < 64) {
    float ss = psum[0][t] + psum[1][t] + psum[2][t] + psum[3][t];
    rstd[t] = rsqrtf(ss * (1.0f / kC) + kEps);
  }
  __syncthreads();
#pragma unroll
  for (int cc = 0; cc < 16; ++cc) {
    int c = cg * 16 + cc;
    knT[c][sl] = kt[sl][c] * rstd[sl] * nk_w[c];
  }
  __syncthreads();

  // projection: thread (e = t&63, sg = t>>6) handles 16 s rows
  const int e = t & 63, sg = t >> 6;
  float acc[16];
  float bias = bk[e];
#pragma unroll
  for (int ss = 0; ss < 16; ++ss) acc[ss] = bias;
  const float* wrow = wk + e * kC;
  for (int c = 0; c < kC; ++c) {
    float w = wrow[c];
    const float4* xr = reinterpret_cast<const float4*>(&knT[c][sg * 16]);
    float4 x0 = xr[0], x1 = xr[1], x2 = xr[2], x3 = xr[3];   // broadcast
    acc[0]  = fmaf(w, x0.x, acc[0]);  acc[1]  = fmaf(w, x0.y, acc[1]);
    acc[2]  = fmaf(w, x0.z, acc[2]);  acc[3]  = fmaf(w, x0.w, acc[3]);
    acc[4]  = fmaf(w, x1.x, acc[4]);  acc[5]  = fmaf(w, x1.y, acc[5]);
    acc[6]  = fmaf(w, x1.z, acc[6]);  acc[7]  = fmaf(w, x1.w, acc[7]);
    acc[8]  = fmaf(w, x2.x, acc[8]);  acc[9]  = fmaf(w, x2.y, acc[9]);
    acc[10] = fmaf(w, x2.z, acc[10]); acc[11] = fmaf(w, x2.w, acc[11]);
    acc[12] = fmaf(w, x3.x, acc[12]); acc[13] = fmaf(w, x3.y, acc[13]);
    acc[14] = fmaf(w, x3.z, acc[14]); acc[15] = fmaf(w, x3.w, acc[15]);
  }
#pragma unroll
  for (int ss = 0; ss < 16; ++ss) {
    kp[((size_t)b * kS + s0 + sg * 16 + ss) * kC + e] = f2bf(acc[ss]);
  }
}

// ---------------------------------------------------------------------------
// q path: 3x3 conv + RMSNorm + projection (*0.25) -> qp bf16 [B,S,64]
// grid (576, 8), 256 threads; wave pw handles pixel s = bx*4 + pw.
// ---------------------------------------------------------------------------
__global__ __launch_bounds__(256) void q_path(
    const float* __restrict__ q, const float* __restrict__ conv_w,
    const float* __restrict__ nq_w, const float* __restrict__ wq,
    const float* __restrict__ bq, short* __restrict__ qp) {
  __shared__ float qf[4][kC * 9];
  __shared__ float qn[4][kC];
  const int b = blockIdx.y;
  const int t = threadIdx.x;
  const int lane = t & 63;
  const int pw = t >> 6;
  const int s = blockIdx.x * 4 + pw;
  const int h = s / kW, w = s % kW;

  const float* qb = q + ((size_t)b * kC + lane) * (kH * kW);
#pragma unroll
  for (int tap = 0; tap < 9; ++tap) {
    int hh = h + tap / 3 - 1;
    int ww = w + tap % 3 - 1;
    float val = 0.f;
    if (hh >= 0 && hh < kH && ww >= 0 && ww < kW) val = qb[hh * kW + ww];
    qf[pw][lane * 9 + tap] = val;
  }
  __syncthreads();

  const float* wr = conv_w + lane * (kC * 9);
  float acc = 0.f;
#pragma unroll 4
  for (int idx = 0; idx < kC * 9; idx += 4) {
    float4 wv = *reinterpret_cast<const float4*>(wr + idx);
    const float* qv = &qf[pw][idx];
    acc = fmaf(qv[0], wv.x, acc);
    acc = fmaf(qv[1], wv.y, acc);
    acc = fmaf(qv[2], wv.z, acc);
    acc = fmaf(qv[3], wv.w, acc);
  }

  float ssum = acc * acc;
#pragma unroll
  for (int off = 32; off; off >>= 1) ssum += __shfl_xor(ssum, off, 64);
  float rinv = rsqrtf(ssum * (1.0f / kC) + kEps);
  qn[pw][lane] = acc * rinv * nq_w[lane];
  __syncthreads();

  const float* prow = wq + lane * kC;
  float a2 = bq[lane];
#pragma unroll
  for (int c = 0; c < kC; c += 4) {
    float4 wv = *reinterpret_cast<const float4*>(prow + c);
    a2 = fmaf(qn[pw][c + 0], wv.x, a2);
    a2 = fmaf(qn[pw][c + 1], wv.y, a2);
    a2 = fmaf(qn[pw][c + 2], wv.z, a2);
    a2 = fmaf(qn[pw][c + 3], wv.w, a2);
  }
  qp[((size_t)b * kS + s) * kC + lane] = f2bf(a2 * 0.25f);
}

// ---------------------------------------------------------------------------
// MFMA attention. grid (144, 8), 256 thr (4 waves), i-tile = 16.
// Head h dot (K=16) inside a K=32 MFMA by quad-masking the K operand:
// d = 32*dw + quad*8 + r  -> head = 2*dw + (quad>>1); keep iff (quad>>1)==(h&1).
// Sweep1: S^T = mfma(A=Kmask, B=Q) -> lane holds 4 j's of one i -> online m,l.
// Sweep2: S = mfma(A=Q, B=Kmask) -> w(i,j) -> wtile (bf16, A-layout via LDS)
//         -> PV: mfma(A=P, B=V) with V frags gathered from raw v [b][dv][s].
// ---------------------------------------------------------------------------
__global__ __launch_bounds__(256) void attn_mfma(
    const short* __restrict__ qp, const short* __restrict__ kp,
    const float* __restrict__ v, float* __restrict__ out) {
  __shared__ float pm[4][4][16][4];   // [ws][quad][i][h]
  __shared__ float pl[4][4][16][4];
  __shared__ float Mf[16][4];
  __shared__ float Li[16][4];         // 0.25 / L
  __shared__ __align__(16) short wtile[16][72];   // [i][j_local] bf16, pad 72

  const int b = blockIdx.y;
  const int i0 = blockIdx.x * 16;
  const int t = threadIdx.x;
  const int ws = t >> 6;      // wave: j-sub (sweeps), dv-tile (PV)
  const int L = t & 63;
  const int quad = L >> 4;
  const int l16 = L & 15;
  const int qhi = quad >> 1;  // which head of the 32-d window this quad covers

  const short8 zero8 = {0, 0, 0, 0, 0, 0, 0, 0};

  // resident Q fragments: row i = i0+l16; window dw: bytes 16*(dw*4+quad)
  const short8* qrow = reinterpret_cast<const short8*>(
      qp + ((size_t)b * kS + i0 + l16) * kC);
  const short8 qf0 = qrow[quad];
  const short8 qf1 = qrow[4 + quad];

  // ---- sweep 1: online stats ----
  float m[4] = {-1e30f, -1e30f, -1e30f, -1e30f};
  float l[4] = {0.f, 0.f, 0.f, 0.f};

  for (int jt = 0; jt < kS / 64; ++jt) {
    const int j = jt * 64 + ws * 16 + l16;
    const short8* krow = reinterpret_cast<const short8*>(
        kp + ((size_t)b * kS + j) * kC);
    const short8 kf0 = krow[quad];
    const short8 kf1 = krow[4 + quad];
#pragma unroll
    for (int h = 0; h < 4; ++h) {
      short8 kw = (h >> 1) ? kf1 : kf0;
      short8 a = ((h & 1) == qhi) ? kw : zero8;          // masked K (A op)
      short8 bb = (h >> 1) ? qf1 : qf0;                  // Q (B op)
      f32x4 zc = {0.f, 0.f, 0.f, 0.f};
      f32x4 sv = __builtin_amdgcn_mfma_f32_16x16x32_bf16(a, bb, zc, 0, 0, 0);
      // lane holds S^T rows j_local = quad*4+reg (4 j's), col i = l16
      float mx = fmaxf(fmaxf(sv[0], sv[1]), fmaxf(sv[2], sv[3]));
      float nm = fmaxf(m[h], mx);
      l[h] = l[h] * __expf(m[h] - nm) + __expf(sv[0] - nm) + __expf(sv[1] - nm)
           + __expf(sv[2] - nm) + __expf(sv[3] - nm);
      m[h] = nm;
    }
  }
#pragma unroll
  for (int h = 0; h < 4; ++h) {
    pm[ws][quad][l16][h] = m[h];
    pl[ws][quad][l16][h] = l[h];
  }
  __syncthreads();
  if (t < 64) {
    const int i = t >> 2, h = t & 3;
    float M = -1e30f;
#pragma unroll
    for (int a = 0; a < 4; ++a)
#pragma unroll
      for (int c = 0; c < 4; ++c) M = fmaxf(M, pm[a][c][i][h]);
    float Ls = 0.f;
#pragma unroll
    for (int a = 0; a < 4; ++a)
#pragma unroll
      for (int c = 0; c < 4; ++c)
        Ls += pl[a][c][i][h] * __expf(pm[a][c][i][h] - M);
    Mf[i][h] = M;
    Li[i][h] = 0.25f / Ls;
  }
  __syncthreads();

  // per-lane final stats for rows i = quad*4 + reg
  float Mr[4][4], Lr[4][4];
#pragma unroll
  for (int reg = 0; reg < 4; ++reg)
#pragma unroll
    for (int h = 0; h < 4; ++h) {
      Mr[reg][h] = Mf[quad * 4 + reg][h];
      Lr[reg][h] = Li[quad * 4 + reg][h];
    }

  // ---- sweep 2: weights + PV ----
  f32x4 Oacc = {0.f, 0.f, 0.f, 0.f};

  for (int jt = 0; jt < kS / 64; ++jt) {
    const int j = jt * 64 + ws * 16 + l16;
    const short8* krow = reinterpret_cast<const short8*>(
        kp + ((size_t)b * kS + j) * kC);
    const short8 kf0 = krow[quad];
    const short8 kf1 = krow[4 + quad];
    f32x4 sv[4];
#pragma unroll
    for (int h = 0; h < 4; ++h) {
      short8 kw = (h >> 1) ? kf1 : kf0;
      short8 bb = ((h & 1) == qhi) ? kw : zero8;         // masked K (B op)
      short8 a = (h >> 1) ? qf1 : qf0;                   // Q (A op)
      f32x4 zc = {0.f, 0.f, 0.f, 0.f};
      sv[h] = __builtin_amdgcn_mfma_f32_16x16x32_bf16(a, bb, zc, 0, 0, 0);
      // lane holds S rows i = quad*4+reg, col j_local(sub) = l16
    }
#pragma unroll
    for (int reg = 0; reg < 4; ++reg) {
      float wsum = __expf(sv[0][reg] - Mr[reg][0]) * Lr[reg][0]
                 + __expf(sv[1][reg] - Mr[reg][1]) * Lr[reg][1]
                 + __expf(sv[2][reg] - Mr[reg][2]) * Lr[reg][2]
                 + __expf(sv[3][reg] - Mr[reg][3]) * Lr[reg][3];
      wtile[quad * 4 + reg][ws * 16 + l16] = f2bf(wsum);
    }
    __syncthreads();

    // PV: wave ws owns dv-tile ws
#pragma unroll
    for (int jc = 0; jc < 2; ++jc) {
      short8 pf = *reinterpret_cast<const short8*>(
          &wtile[l16][jc * 32 + quad * 8]);              // A = P[i=l16][j..]
      const float* vp = v + ((size_t)b * kC + ws * 16 + l16) * kS
                          + jt * 64 + jc * 32 + quad * 8;
      float4 va = *reinterpret_cast<const float4*>(vp);
      float4 vb = *reinterpret_cast<const float4*>(vp + 4);
      short8 vf;
      vf[0] = f2bf(va.x); vf[1] = f2bf(va.y); vf[2] = f2bf(va.z); vf[3] = f2bf(va.w);
      vf[4] = f2bf(vb.x); vf[5] = f2bf(vb.y); vf[6] = f2bf(vb.z); vf[7] = f2bf(vb.w);
      Oacc = __builtin_amdgcn_mfma_f32_16x16x32_bf16(pf, vf, Oacc, 0, 0, 0);
    }
    __syncthreads();
  }

  // store: rows i = quad*4+reg, col dv = ws*16 + l16
#pragma unroll
  for (int reg = 0; reg < 4; ++reg) {
    out[((size_t)b * kS + i0 + quad * 4 + reg) * kC + ws * 16 + l16] = Oacc[reg];
  }
}

// ---------------------------------------------------------------------------
extern "C" void kernel_launch(void* const* d_in, const int* in_sizes, int n_in,
                              void* d_out, int out_size, void* d_ws, size_t ws_size,
                              hipStream_t stream) {
  const float* q      = (const float*)d_in[0];
  const float* k      = (const float*)d_in[1];
  const float* v      = (const float*)d_in[2];
  const float* conv_w = (const float*)d_in[3];
  const float* nq_w   = (const float*)d_in[4];
  const float* nk_w   = (const float*)d_in[5];
  const float* wq     = (const float*)d_in[6];
  const float* bq     = (const float*)d_in[7];
  const float* wk     = (const float*)d_in[8];
  const float* bk     = (const float*)d_in[9];
  float* out = (float*)d_out;

  const size_t N = (size_t)kB * kS * kC;
  short* kp = (short*)d_ws;        // bf16 [B,S,64]
  short* qp = kp + N;              // bf16 [B,S,64]

  k_path<<<dim3(kS / 64, kB), 256, 0, stream>>>(k, nk_w, wk, bk, kp);
  q_path<<<dim3(kS / 4, kB), 256, 0, stream>>>(q, conv_w, nq_w, wq, bq, qp);
  attn_mfma<<<dim3(kS / 16, kB), 256, 0, stream>>>(qp, kp, v, out);
}

// Round 5
// 239.283 us; speedup vs baseline: 4.5847x; 2.4914x over previous
//
#include <hip/hip_runtime.h>
#include <hip/hip_bf16.h>

namespace {
constexpr int kB = 8;
constexpr int kC = 64;
constexpr int kH = 48;
constexpr int kW = 48;
constexpr int kS = kH * kW;          // 2304
constexpr float kEps = 1.1920929e-07f;
}

typedef __attribute__((ext_vector_type(8))) short short8;   // 8 bf16 (4 VGPR)
typedef __attribute__((ext_vector_type(4))) float f32x4;

// fp32 -> bf16 (round-nearest-even), bit-level
__device__ __forceinline__ short f2bf(float x) {
  unsigned u = __float_as_uint(x);
  u += 0x7fffu + ((u >> 16) & 1u);
  return (short)(u >> 16);
}
__device__ __forceinline__ float bf2f(short s) {
  return __uint_as_float(((unsigned)(unsigned short)s) << 16);
}

// ---------------------------------------------------------------------------
// P0: weight prep. wq,wk -> bf16 [e][c]; conv_w [co][ci][tap] -> wt2 bf16
// [tap][co][ci] (ci innermost => contiguous MFMA B frags).
// total 45056 elems, grid 176x256.
// ---------------------------------------------------------------------------
__global__ __launch_bounds__(256) void prep_weights(
    const float* __restrict__ wq, const float* __restrict__ wk,
    const float* __restrict__ conv_w,
    short* __restrict__ wqb, short* __restrict__ wkb, short* __restrict__ wt2) {
  int idx = blockIdx.x * 256 + threadIdx.x;
  if (idx < 4096) {
    wqb[idx] = f2bf(wq[idx]);
  } else if (idx < 8192) {
    wkb[idx - 4096] = f2bf(wk[idx - 4096]);
  } else if (idx < 8192 + 64 * 64 * 9) {
    int i = idx - 8192;
    int ci = i & 63, co = (i >> 6) & 63, tap = i >> 12;
    wt2[i] = f2bf(conv_w[co * 576 + ci * 9 + tap]);
  }
}

// ---------------------------------------------------------------------------
// P1: transpose q,k from [b][c][s] fp32 -> [b][s][c] bf16. grid (36, 16).
// ---------------------------------------------------------------------------
__global__ __launch_bounds__(256) void qk_transpose(
    const float* __restrict__ q, const float* __restrict__ k,
    short* __restrict__ qt, short* __restrict__ kt) {
  __shared__ float tile[64][65];
  const int zz = blockIdx.y;       // b*2 + which
  const int b = zz >> 1;
  const float* src = (zz & 1) ? k : q;
  short* dst = (zz & 1) ? kt : qt;
  const int s0 = blockIdx.x * 64;
  const int tx = threadIdx.x & 63;
  const int ty = threadIdx.x >> 6;
#pragma unroll
  for (int r = 0; r < 16; ++r) {
    int c = r * 4 + ty;
    tile[c][tx] = src[((size_t)b * kC + c) * kS + s0 + tx];
  }
  __syncthreads();
#pragma unroll
  for (int r = 0; r < 16; ++r) {
    int s = r * 4 + ty;
    dst[((size_t)b * kS + s0 + s) * kC + tx] = f2bf(tile[tx][s]);
  }
}

// ---------------------------------------------------------------------------
// P2: v fp32 -> bf16 (same [b][c][s] layout). 1.18M elems, 4/thread.
// ---------------------------------------------------------------------------
__global__ __launch_bounds__(256) void v_cast(
    const float* __restrict__ v, short* __restrict__ vt) {
  int idx = (blockIdx.x * 256 + threadIdx.x) * 4;
  float4 x = *reinterpret_cast<const float4*>(v + idx);
  int2 o;
  o.x = ((int)(unsigned short)f2bf(x.y) << 16) | (unsigned short)f2bf(x.x);
  o.y = ((int)(unsigned short)f2bf(x.w) << 16) | (unsigned short)f2bf(x.z);
  *reinterpret_cast<int2*>(vt + idx) = o;
}

// ---------------------------------------------------------------------------
// K1: q path via MFMA. grid (36, 8), 256 thr (4 waves x 16 rows).
// conv = 9-tap GEMM: acc[co_tile] += A(im2col rows, masked) x B(wt2[tap]).
// Then RMSNorm (intra-quad shuffles), LDS round-trip to A-layout,
// projection GEMM with wqb, +bq, *0.25 -> qp bf16 [b][s][64].
// ---------------------------------------------------------------------------
__global__ __launch_bounds__(256) void q_gemm(
    const short* __restrict__ qt, const short* __restrict__ wt2,
    const float* __restrict__ nq_w, const short* __restrict__ wqb,
    const float* __restrict__ bq, short* __restrict__ qp) {
  __shared__ __align__(16) short ln[4][16][80];   // per-wave normalized tile
  const int b = blockIdx.y;
  const int t = threadIdx.x;
  const int ws = t >> 6;
  const int L = t & 63;
  const int quad = L >> 4;
  const int l16 = L & 15;
  const int sBase = blockIdx.x * 64 + ws * 16;
  const int s = sBase + l16;            // this lane's A row (m = l16)
  const int h = s / kW, w = s % kW;

  const short8 zero8 = {0, 0, 0, 0, 0, 0, 0, 0};
  f32x4 acc[4] = {{0.f, 0.f, 0.f, 0.f}, {0.f, 0.f, 0.f, 0.f},
                  {0.f, 0.f, 0.f, 0.f}, {0.f, 0.f, 0.f, 0.f}};

#pragma unroll
  for (int tap = 0; tap < 9; ++tap) {
    const int dh = tap / 3 - 1, dw = tap % 3 - 1;
    const bool valid = (unsigned)(h + dh) < (unsigned)kH &&
                       (unsigned)(w + dw) < (unsigned)kW;
    const int srow = valid ? (s + dh * kW + dw) : s;
    const short8* ap = reinterpret_cast<const short8*>(
        qt + ((size_t)b * kS + srow) * kC);
#pragma unroll
    for (int kh = 0; kh < 2; ++kh) {
      short8 af = ap[kh * 4 + quad];
      af = valid ? af : zero8;
      const short* wb = wt2 + tap * 4096 + l16 * kC + kh * 32 + quad * 8;
#pragma unroll
      for (int nt = 0; nt < 4; ++nt) {
        short8 bf = *reinterpret_cast<const short8*>(wb + nt * 16 * kC);
        acc[nt] = __builtin_amdgcn_mfma_f32_16x16x32_bf16(af, bf, acc[nt], 0, 0, 0);
      }
    }
  }

  // RMSNorm: D rows = quad*4+reg, cols = nt*16+l16. Row sums over 64 cols.
  float rstd[4];
#pragma unroll
  for (int reg = 0; reg < 4; ++reg) {
    float pr = acc[0][reg] * acc[0][reg] + acc[1][reg] * acc[1][reg]
             + acc[2][reg] * acc[2][reg] + acc[3][reg] * acc[3][reg];
    pr += __shfl_xor(pr, 1, 64);
    pr += __shfl_xor(pr, 2, 64);
    pr += __shfl_xor(pr, 4, 64);
    pr += __shfl_xor(pr, 8, 64);
    rstd[reg] = rsqrtf(pr * (1.0f / kC) + kEps);
  }
#pragma unroll
  for (int nt = 0; nt < 4; ++nt) {
    float g = nq_w[nt * 16 + l16];
#pragma unroll
    for (int reg = 0; reg < 4; ++reg) {
      ln[ws][quad * 4 + reg][nt * 16 + l16] = f2bf(acc[nt][reg] * rstd[reg] * g);
    }
  }
  __syncthreads();

  // projection: A from LDS (m=l16), B = wqb[e][c]
  f32x4 acc2[4] = {{0.f, 0.f, 0.f, 0.f}, {0.f, 0.f, 0.f, 0.f},
                   {0.f, 0.f, 0.f, 0.f}, {0.f, 0.f, 0.f, 0.f}};
#pragma unroll
  for (int kh = 0; kh < 2; ++kh) {
    short8 af = *reinterpret_cast<const short8*>(&ln[ws][l16][kh * 32 + quad * 8]);
#pragma unroll
    for (int nt = 0; nt < 4; ++nt) {
      short8 bf = *reinterpret_cast<const short8*>(
          wqb + (nt * 16 + l16) * kC + kh * 32 + quad * 8);
      acc2[nt] = __builtin_amdgcn_mfma_f32_16x16x32_bf16(af, bf, acc2[nt], 0, 0, 0);
    }
  }
#pragma unroll
  for (int nt = 0; nt < 4; ++nt) {
    const int e = nt * 16 + l16;
    float bias = bq[e];
#pragma unroll
    for (int reg = 0; reg < 4; ++reg) {
      qp[((size_t)b * kS + sBase + quad * 4 + reg) * kC + e] =
          f2bf((acc2[nt][reg] + bias) * 0.25f);
    }
  }
}

// ---------------------------------------------------------------------------
// K2: k path via MFMA. grid (36, 8), 4 waves x 16 rows, no LDS.
// A frags (rows m=l16) from kt; in-register RMSNorm (shuffle across quads);
// projection with wkb; +bk -> kp bf16.
// ---------------------------------------------------------------------------
__global__ __launch_bounds__(256) void k_gemm(
    const short* __restrict__ kt, const float* __restrict__ nk_w,
    const short* __restrict__ wkb, const float* __restrict__ bk,
    short* __restrict__ kp) {
  const int b = blockIdx.y;
  const int t = threadIdx.x;
  const int ws = t >> 6;
  const int L = t & 63;
  const int quad = L >> 4;
  const int l16 = L & 15;
  const int sBase = blockIdx.x * 64 + ws * 16;
  const int s = sBase + l16;

  const short8* ap = reinterpret_cast<const short8*>(
      kt + ((size_t)b * kS + s) * kC);
  short8 af0 = ap[quad];
  short8 af1 = ap[4 + quad];

  float xs[16];
#pragma unroll
  for (int j = 0; j < 8; ++j) { xs[j] = bf2f(af0[j]); xs[8 + j] = bf2f(af1[j]); }
  float sum = 0.f;
#pragma unroll
  for (int j = 0; j < 16; ++j) sum = fmaf(xs[j], xs[j], sum);
  sum += __shfl_xor(sum, 16, 64);
  sum += __shfl_xor(sum, 32, 64);
  float rstd = rsqrtf(sum * (1.0f / kC) + kEps);

  const float* n0 = nk_w + quad * 8;
#pragma unroll
  for (int j = 0; j < 8; ++j) {
    af0[j] = f2bf(xs[j] * rstd * n0[j]);
    af1[j] = f2bf(xs[8 + j] * rstd * n0[32 + j]);
  }

  f32x4 acc[4] = {{0.f, 0.f, 0.f, 0.f}, {0.f, 0.f, 0.f, 0.f},
                  {0.f, 0.f, 0.f, 0.f}, {0.f, 0.f, 0.f, 0.f}};
#pragma unroll
  for (int nt = 0; nt < 4; ++nt) {
    short8 bf0 = *reinterpret_cast<const short8*>(
        wkb + (nt * 16 + l16) * kC + quad * 8);
    short8 bf1 = *reinterpret_cast<const short8*>(
        wkb + (nt * 16 + l16) * kC + 32 + quad * 8);
    acc[nt] = __builtin_amdgcn_mfma_f32_16x16x32_bf16(af0, bf0, acc[nt], 0, 0, 0);
    acc[nt] = __builtin_amdgcn_mfma_f32_16x16x32_bf16(af1, bf1, acc[nt], 0, 0, 0);
  }
#pragma unroll
  for (int nt = 0; nt < 4; ++nt) {
    const int e = nt * 16 + l16;
    float bias = bk[e];
#pragma unroll
    for (int reg = 0; reg < 4; ++reg) {
      kp[((size_t)b * kS + sBase + quad * 4 + reg) * kC + e] =
          f2bf(acc[nt][reg] + bias);
    }
  }
}

// ---------------------------------------------------------------------------
// K3: MFMA attention (round-4 structure; v now pre-cast bf16).
// ---------------------------------------------------------------------------
__global__ __launch_bounds__(256) void attn_mfma(
    const short* __restrict__ qp, const short* __restrict__ kp,
    const short* __restrict__ vt, float* __restrict__ out) {
  __shared__ float pm[4][4][16][4];   // [ws][quad][i][h]
  __shared__ float pl[4][4][16][4];
  __shared__ float Mf[16][4];
  __shared__ float Li[16][4];         // 0.25 / L
  __shared__ __align__(16) short wtile[16][72];

  const int b = blockIdx.y;
  const int i0 = blockIdx.x * 16;
  const int t = threadIdx.x;
  const int ws = t >> 6;
  const int L = t & 63;
  const int quad = L >> 4;
  const int l16 = L & 15;
  const int qhi = quad >> 1;

  const short8 zero8 = {0, 0, 0, 0, 0, 0, 0, 0};

  const short8* qrow = reinterpret_cast<const short8*>(
      qp + ((size_t)b * kS + i0 + l16) * kC);
  const short8 qf0 = qrow[quad];
  const short8 qf1 = qrow[4 + quad];

  // ---- sweep 1: online stats ----
  float m[4] = {-1e30f, -1e30f, -1e30f, -1e30f};
  float l[4] = {0.f, 0.f, 0.f, 0.f};

  for (int jt = 0; jt < kS / 64; ++jt) {
    const int j = jt * 64 + ws * 16 + l16;
    const short8* krow = reinterpret_cast<const short8*>(
        kp + ((size_t)b * kS + j) * kC);
    const short8 kf0 = krow[quad];
    const short8 kf1 = krow[4 + quad];
#pragma unroll
    for (int h = 0; h < 4; ++h) {
      short8 kw = (h >> 1) ? kf1 : kf0;
      short8 a = ((h & 1) == qhi) ? kw : zero8;
      short8 bb = (h >> 1) ? qf1 : qf0;
      f32x4 zc = {0.f, 0.f, 0.f, 0.f};
      f32x4 sv = __builtin_amdgcn_mfma_f32_16x16x32_bf16(a, bb, zc, 0, 0, 0);
      float mx = fmaxf(fmaxf(sv[0], sv[1]), fmaxf(sv[2], sv[3]));
      float nm = fmaxf(m[h], mx);
      l[h] = l[h] * __expf(m[h] - nm) + __expf(sv[0] - nm) + __expf(sv[1] - nm)
           + __expf(sv[2] - nm) + __expf(sv[3] - nm);
      m[h] = nm;
    }
  }
#pragma unroll
  for (int h = 0; h < 4; ++h) {
    pm[ws][quad][l16][h] = m[h];
    pl[ws][quad][l16][h] = l[h];
  }
  __syncthreads();
  if (t < 64) {
    const int i = t >> 2, h = t & 3;
    float M = -1e30f;
#pragma unroll
    for (int a = 0; a < 4; ++a)
#pragma unroll
      for (int c = 0; c < 4; ++c) M = fmaxf(M, pm[a][c][i][h]);
    float Ls = 0.f;
#pragma unroll
    for (int a = 0; a < 4; ++a)
#pragma unroll
      for (int c = 0; c < 4; ++c)
        Ls += pl[a][c][i][h] * __expf(pm[a][c][i][h] - M);
    Mf[i][h] = M;
    Li[i][h] = 0.25f / Ls;
  }
  __syncthreads();

  float Mr[4][4], Lr[4][4];
#pragma unroll
  for (int reg = 0; reg < 4; ++reg)
#pragma unroll
    for (int h = 0; h < 4; ++h) {
      Mr[reg][h] = Mf[quad * 4 + reg][h];
      Lr[reg][h] = Li[quad * 4 + reg][h];
    }

  // ---- sweep 2: weights + PV ----
  f32x4 Oacc = {0.f, 0.f, 0.f, 0.f};

  for (int jt = 0; jt < kS / 64; ++jt) {
    const int j = jt * 64 + ws * 16 + l16;
    const short8* krow = reinterpret_cast<const short8*>(
        kp + ((size_t)b * kS + j) * kC);
    const short8 kf0 = krow[quad];
    const short8 kf1 = krow[4 + quad];
    f32x4 sv[4];
#pragma unroll
    for (int h = 0; h < 4; ++h) {
      short8 kw = (h >> 1) ? kf1 : kf0;
      short8 bb = ((h & 1) == qhi) ? kw : zero8;
      short8 a = (h >> 1) ? qf1 : qf0;
      f32x4 zc = {0.f, 0.f, 0.f, 0.f};
      sv[h] = __builtin_amdgcn_mfma_f32_16x16x32_bf16(a, bb, zc, 0, 0, 0);
    }
#pragma unroll
    for (int reg = 0; reg < 4; ++reg) {
      float wsum = __expf(sv[0][reg] - Mr[reg][0]) * Lr[reg][0]
                 + __expf(sv[1][reg] - Mr[reg][1]) * Lr[reg][1]
                 + __expf(sv[2][reg] - Mr[reg][2]) * Lr[reg][2]
                 + __expf(sv[3][reg] - Mr[reg][3]) * Lr[reg][3];
      wtile[quad * 4 + reg][ws * 16 + l16] = f2bf(wsum);
    }
    __syncthreads();

#pragma unroll
    for (int jc = 0; jc < 2; ++jc) {
      short8 pf = *reinterpret_cast<const short8*>(
          &wtile[l16][jc * 32 + quad * 8]);
      short8 vf = *reinterpret_cast<const short8*>(
          vt + ((size_t)b * kC + ws * 16 + l16) * kS + jt * 64 + jc * 32 + quad * 8);
      Oacc = __builtin_amdgcn_mfma_f32_16x16x32_bf16(pf, vf, Oacc, 0, 0, 0);
    }
    __syncthreads();
  }

#pragma unroll
  for (int reg = 0; reg < 4; ++reg) {
    out[((size_t)b * kS + i0 + quad * 4 + reg) * kC + ws * 16 + l16] = Oacc[reg];
  }
}

// ---------------------------------------------------------------------------
extern "C" void kernel_launch(void* const* d_in, const int* in_sizes, int n_in,
                              void* d_out, int out_size, void* d_ws, size_t ws_size,
                              hipStream_t stream) {
  const float* q      = (const float*)d_in[0];
  const float* k      = (const float*)d_in[1];
  const float* v      = (const float*)d_in[2];
  const float* conv_w = (const float*)d_in[3];
  const float* nq_w   = (const float*)d_in[4];
  const float* nk_w   = (const float*)d_in[5];
  const float* wq     = (const float*)d_in[6];
  const float* bq     = (const float*)d_in[7];
  const float* wk     = (const float*)d_in[8];
  const float* bk     = (const float*)d_in[9];
  float* out = (float*)d_out;

  const size_t N = (size_t)kB * kS * kC;   // 1,179,648
  short* qt  = (short*)d_ws;     // bf16 [b][s][c]
  short* kt  = qt + N;
  short* vt  = kt + N;           // bf16 [b][c][s]
  short* qp  = vt + N;           // bf16 [b][s][64]
  short* kp  = qp + N;
  short* wqb = kp + N;           // bf16 [64][64]
  short* wkb = wqb + 4096;
  short* wt2 = wkb + 4096;       // bf16 [9][64][64]

  prep_weights<<<176, 256, 0, stream>>>(wq, wk, conv_w, wqb, wkb, wt2);
  qk_transpose<<<dim3(kS / 64, kB * 2), 256, 0, stream>>>(q, k, qt, kt);
  v_cast<<<N / 1024, 256, 0, stream>>>(v, vt);
  q_gemm<<<dim3(kS / 64, kB), 256, 0, stream>>>(qt, wt2, nq_w, wqb, bq, qp);
  k_gemm<<<dim3(kS / 64, kB), 256, 0, stream>>>(kt, nk_w, wkb, bk, kp);
  attn_mfma<<<dim3(kS / 16, kB), 256, 0, stream>>>(qp, kp, vt, out);
}